// Round 12
// baseline (522.858 us; speedup 1.0000x reference)
//
#include <hip/hip_runtime.h>
#include <hip/hip_fp16.h>

// GCN link-prediction forward. All random-gather stages use XCD-sliced,
// slice-major L2-resident fp16 tables (slice = blockIdx & (S-1)) with
// full-width 16B/lane converged loads: agg1 g1s[8][N][32], agg2 g2s[4][N][32]
// -> zs[4][N][32], decode reads zs. fp16 MFMA GEMMs; parallel prefix scan.
// Inputs: x[N,256] f32, train_edges[2,E] i32, pos[2,E] i32, neg[2,E] i32,
//         W1[256,256], b1[256], W2[256,128], b2[128]  (all f32)
// Output: logits[2E] f32.

#define NFEAT 256
#define HID   256
#define OUTF  128

typedef _Float16 f16x8 __attribute__((ext_vector_type(8)));
typedef _Float16 f16x2 __attribute__((ext_vector_type(2)));
typedef float    f32x4 __attribute__((ext_vector_type(4)));

// ---------------- degree ----------------
__global__ void k_init_deg(float* __restrict__ deg, int n) {
    int i = blockIdx.x * blockDim.x + threadIdx.x;
    if (i < n) deg[i] = 1.0f;   // self-loop
}

__global__ void k_count_deg(const int* __restrict__ ei, float* __restrict__ deg, int E) {
    int e = blockIdx.x * blockDim.x + threadIdx.x;
    if (e < E) atomicAdd(&deg[ei[E + e]], 1.0f);   // dst row
}

// ---------------- parallel scan, pass 1: per-block exclusive scan ----------------
__global__ __launch_bounds__(1024) void k_scan1(
        const float* __restrict__ deg, int* __restrict__ excl,
        int* __restrict__ bsum, int n) {
    __shared__ int swsum[16];
    const int t = threadIdx.x, wave = t >> 6, lane = t & 63;
    const int i = blockIdx.x * 1024 + t;
    int v = (i < n) ? (int)deg[i] - 1 : 0;
    int sc = v;
#pragma unroll
    for (int off = 1; off < 64; off <<= 1) {
        int y = __shfl_up(sc, off);
        if (lane >= off) sc += y;
    }
    if (lane == 63) swsum[wave] = sc;
    __syncthreads();
    if (t < 16) {
        int w = swsum[t];
        int scw = w;
#pragma unroll
        for (int off = 1; off < 16; off <<= 1) {
            int y = __shfl_up(scw, off);
            if (t >= off) scw += y;
        }
        swsum[t] = scw - w;
        if (t == 15) bsum[blockIdx.x] = scw;
    }
    __syncthreads();
    if (i < n) excl[i] = swsum[wave] + (sc - v);
}

// ---------------- pass 2: scan the (<=64) block sums in one wave ----------------
__global__ void k_scan2(int* __restrict__ bsum, int nb) {
    int t = threadIdx.x;          // 64 threads
    int v = (t < nb) ? bsum[t] : 0;
    int sc = v;
#pragma unroll
    for (int off = 1; off < 64; off <<= 1) {
        int y = __shfl_up(sc, off);
        if (t >= off) sc += y;
    }
    if (t < nb) bsum[t] = sc - v;   // exclusive
    if (t == 63) bsum[nb] = sc;     // grand total
}

// ---------------- pass 3: rowptr/cursor/dinv ----------------
__global__ void k_scan3(float* __restrict__ deg_dinv, const int* __restrict__ excl,
                        const int* __restrict__ bsum, int* __restrict__ rowptr,
                        int* __restrict__ cursor, int n, int nb) {
    int i = blockIdx.x * blockDim.x + threadIdx.x;
    if (i < n) {
        int rp = excl[i] + bsum[i >> 10];
        rowptr[i] = rp;
        cursor[i] = rp;
        deg_dinv[i] = rsqrtf(deg_dinv[i]);
    } else if (i == n) {
        rowptr[n] = bsum[nb];
    }
}

// ---------------- fill CSR adjacency (src ids grouped by dst) ----------------
__global__ void k_fill(const int* __restrict__ ei, int* __restrict__ cursor,
                       int* __restrict__ eidx, int E) {
    int e = blockIdx.x * blockDim.x + threadIdx.x;
    if (e < E) {
        int s = ei[e];
        int d = ei[E + e];
        int p = atomicAdd(&cursor[d], 1);
        eidx[p] = s;
    }
}

// ---------------- W transpose+convert: Wt[m][k] = (half)W[k][m] ----------------
__global__ __launch_bounds__(256) void k_wt(const float* __restrict__ W,
                                            __half* __restrict__ Wt, int K, int M) {
    __shared__ float tile[32][33];
    int k0 = blockIdx.x * 32, m0 = blockIdx.y * 32;
    int tx = threadIdx.x & 31, ty = threadIdx.x >> 5;  // ty 0..7
#pragma unroll
    for (int r = 0; r < 4; ++r)
        tile[ty + r * 8][tx] = W[(size_t)(k0 + ty + r * 8) * M + m0 + tx];
    __syncthreads();
#pragma unroll
    for (int r = 0; r < 4; ++r)
        Wt[(size_t)(m0 + ty + r * 8) * K + k0 + tx] = __float2half(tile[tx][ty + r * 8]);
}

// ---------------- MFMA GEMM: out = (half)(dinv[r] * A @ Wt^T) ----------------
// Block: 256 threads = 4 waves (2x2). Block tile (2*MT*16) x 128, wave (MT*16) x 64.
// A: [n][K] (f32 if AF32 else f16). Wt: [M][K] f16. K % 32 == 0.
// Output SLICE-MAJOR: out[(col>>SWL)][row][col&(SW-1)]; SWL=5 -> 32-feat slices.
template <int MT, bool AF32, int SWL>
__global__ __launch_bounds__(256) void k_gemm_mfma(
        const void* __restrict__ Aptr, const __half* __restrict__ Wt,
        const float* __restrict__ dinv, __half* __restrict__ outp,
        int n, int K, int M) {
    constexpr int BM = 2 * MT * 16;
    __shared__ __half As[BM][40];      // [row][k], +8 pad: 2-way banks (free)
    __shared__ __half Bs[128][40];     // [col][k]
    __shared__ __half Cs[4][16][72];   // per-wave C repack (16B-aligned rows)

    const int t    = threadIdx.x;
    const int wave = t >> 6;
    const int lane = t & 63;
    const int row0 = blockIdx.x * BM;
    const int col0 = blockIdx.y * 128;
    const int wm = wave >> 1, wn = wave & 1;
    const int lr = lane & 15;          // fragment m/n index
    const int kq = lane >> 4;          // k-quad: k = kq*8 + j

    f32x4 acc[MT][4];
#pragma unroll
    for (int i = 0; i < MT; ++i)
#pragma unroll
        for (int j = 0; j < 4; ++j) acc[i][j] = (f32x4){0.f, 0.f, 0.f, 0.f};

    for (int k0 = 0; k0 < K; k0 += 32) {
        // ---- stage A tile: BM rows x 32 k ----
        if (AF32) {
            const float* A = (const float*)Aptr;
#pragma unroll
            for (int it = 0; it < BM * 8 / 256; ++it) {
                int q = t + it * 256;
                int r = q >> 3, c4 = q & 7;       // c4: which 4-float chunk
                int gr = min(row0 + r, n - 1);
                float4 v = *(const float4*)&A[(size_t)gr * K + k0 + c4 * 4];
                __half2* dst = (__half2*)&As[r][c4 * 4];
                dst[0] = __floats2half2_rn(v.x, v.y);
                dst[1] = __floats2half2_rn(v.z, v.w);
            }
        } else {
            const __half* A = (const __half*)Aptr;
#pragma unroll
            for (int it = 0; it < BM * 4 / 256; ++it) {
                int q = t + it * 256;
                int r = q >> 2, c8 = q & 3;       // c8: which 8-half chunk
                int gr = min(row0 + r, n - 1);
                *(float4*)&As[r][c8 * 8] = *(const float4*)&A[(size_t)gr * K + k0 + c8 * 8];
            }
        }
        // ---- stage B tile: 128 cols x 32 k from Wt ----
#pragma unroll
        for (int it = 0; it < 2; ++it) {
            int q = t + it * 256;
            int r = q >> 2, c8 = q & 3;
            *(float4*)&Bs[r][c8 * 8] = *(const float4*)&Wt[(size_t)(col0 + r) * K + k0 + c8 * 8];
        }
        __syncthreads();

        f16x8 b[4];
#pragma unroll
        for (int j = 0; j < 4; ++j)
            b[j] = *(const f16x8*)&Bs[wn * 64 + j * 16 + lr][kq * 8];
#pragma unroll
        for (int i = 0; i < MT; ++i) {
            f16x8 a = *(const f16x8*)&As[wm * MT * 16 + i * 16 + lr][kq * 8];
#pragma unroll
            for (int j = 0; j < 4; ++j)
                acc[i][j] = __builtin_amdgcn_mfma_f32_16x16x32_f16(a, b[j], acc[i][j], 0, 0, 0);
        }
        __syncthreads();
    }

    // ---- epilogue: scale by dinv, f16 convert, repack via LDS, slice-major stores ----
    constexpr int SW = 1 << SWL;
#pragma unroll
    for (int i = 0; i < MT; ++i) {
        int gr0 = row0 + wm * MT * 16 + i * 16;
        float dv[4];
#pragma unroll
        for (int r = 0; r < 4; ++r)
            dv[r] = dinv[min(gr0 + kq * 4 + r, n - 1)];
        __syncthreads();   // protect Cs reuse across i iterations
#pragma unroll
        for (int j = 0; j < 4; ++j)
#pragma unroll
            for (int r = 0; r < 4; ++r)
                Cs[wave][kq * 4 + r][j * 16 + lr] = __float2half(acc[i][j][r] * dv[r]);
        __syncthreads();
        int r1 = lane >> 3, c1 = (lane & 7) * 8;
#pragma unroll
        for (int h = 0; h < 2; ++h) {
            int grow = gr0 + r1 + h * 8;
            if (grow < n) {
                int col = col0 + wn * 64 + c1;    // multiple of 8; stays in-slice
                size_t oidx = ((size_t)(col >> SWL) * n + grow) * SW + (col & (SW - 1));
                *(float4*)&outp[oidx] = *(const float4*)&Cs[wave][r1 + h * 8][c1];
            }
        }
    }
}

// ---------------- sliced aggregate: wave per (node, 32-feat slice) ----------
// gsl [S][n][32] f16; 16 edge-slots x 4 lanes x 16B -> 16 rows per load instr.
// RELU+row-major out (agg1) or plain+slice-major out (agg2).
template <int S, bool RELU, bool OUT_SLICED>
__global__ __launch_bounds__(256) void k_aggs(
        const int* __restrict__ rowptr, const int* __restrict__ eidx,
        const __half* __restrict__ gsl, const float* __restrict__ dinv,
        const float* __restrict__ bias, __half* __restrict__ out, int n) {
    const int slice = blockIdx.x & (S - 1);
    const int node  = (blockIdx.x / S) * 4 + (threadIdx.x >> 6);
    const int lane  = threadIdx.x & 63;
    const int es    = lane >> 2;       // edge slot 0..15
    const int fl    = lane & 3;        // 16B chunk within 64B row
    if (node >= n) return;
    const __half* base = gsl + (size_t)slice * n * 32;
    const int j0 = rowptr[node], end = rowptr[node + 1];

    union U { float4 f; __half2 h[4]; };
    float acc[8] = {0.f, 0.f, 0.f, 0.f, 0.f, 0.f, 0.f, 0.f};
    {   // self row: slot 0 only
        U u; u.f = *(const float4*)&base[(size_t)node * 32 + fl * 8];
        if (es == 0) {
#pragma unroll
            for (int k = 0; k < 4; ++k) {
                float2 v = __half22float2(u.h[k]);
                acc[k * 2] += v.x; acc[k * 2 + 1] += v.y;
            }
        }
    }
    if (j0 < end) {
        const int last = end - 1;
        for (int j = j0; j < end; j += 16) {
            int s = eidx[min(j + es, last)];
            U u; u.f = *(const float4*)&base[(size_t)s * 32 + fl * 8];
            if (j + es < end) {
#pragma unroll
                for (int k = 0; k < 4; ++k) {
                    float2 v = __half22float2(u.h[k]);
                    acc[k * 2] += v.x; acc[k * 2 + 1] += v.y;
                }
            }
        }
    }
    // reduce across the 16 edge slots
#pragma unroll
    for (int m = 4; m <= 32; m <<= 1)
#pragma unroll
        for (int k = 0; k < 8; ++k) acc[k] += __shfl_xor(acc[k], m);
    if (es == 0) {
        const float sc = dinv[node];
        const int f0 = slice * 32 + fl * 8;
        U r;
#pragma unroll
        for (int k = 0; k < 4; ++k) {
            float2 bb = *(const float2*)&bias[f0 + k * 2];
            float vx = sc * acc[k * 2]     + bb.x;
            float vy = sc * acc[k * 2 + 1] + bb.y;
            if (RELU) { vx = fmaxf(vx, 0.f); vy = fmaxf(vy, 0.f); }
            r.h[k] = __floats2half2_rn(vx, vy);
        }
        if (OUT_SLICED)
            *(float4*)&out[((size_t)slice * n + node) * 32 + fl * 8] = r.f;
        else
            *(float4*)&out[(size_t)node * (S * 32) + f0] = r.f;
    }
}

// ---------------- decode (sliced): psum[slice][e], 32 edges/wave ----------------
// zs [4][n][32] f16; slice = bx & 3 (XCD-pinned, 3.2MB L2-resident).
__global__ __launch_bounds__(256) void k_decode(
        const int* __restrict__ pos, const int* __restrict__ neg,
        const __half* __restrict__ zs, float* __restrict__ psum, int E, int n) {
    const int slice = blockIdx.x & 3;
    const int wv    = threadIdx.x >> 6;
    const int lane  = threadIdx.x & 63;
    const int eo    = lane >> 1;       // edge within wave (0..31)
    const int h     = lane & 1;        // which 32B half of the 64B rows
    int e = ((blockIdx.x >> 2) * 4 + wv) * 32 + eo;
    if (e >= 2 * E) return;
    int a, b;
    if (e < E) { a = pos[e];     b = pos[E + e]; }
    else       { a = neg[e - E]; b = neg[e];     }   // neg row1 at E + (e-E) = e
    const __half* ra = zs + ((size_t)slice * n + a) * 32 + h * 16;
    const __half* rb = zs + ((size_t)slice * n + b) * 32 + h * 16;
    union U { float4 f; f16x2 d[4]; };
    U a0, a1, b0, b1;
    a0.f = *(const float4*)&ra[0];
    a1.f = *(const float4*)&ra[8];
    b0.f = *(const float4*)&rb[0];
    b1.f = *(const float4*)&rb[8];
    float p = 0.f;
#if __has_builtin(__builtin_amdgcn_fdot2)
#pragma unroll
    for (int k = 0; k < 4; ++k) p = __builtin_amdgcn_fdot2(a0.d[k], b0.d[k], p, false);
#pragma unroll
    for (int k = 0; k < 4; ++k) p = __builtin_amdgcn_fdot2(a1.d[k], b1.d[k], p, false);
#else
#pragma unroll
    for (int k = 0; k < 4; ++k) {
        p += (float)a0.d[k][0] * (float)b0.d[k][0] + (float)a0.d[k][1] * (float)b0.d[k][1];
        p += (float)a1.d[k][0] * (float)b1.d[k][0] + (float)a1.d[k][1] * (float)b1.d[k][1];
    }
#endif
    p += __shfl_xor(p, 1);
    if (h == 0)
        __builtin_nontemporal_store(p, &psum[(size_t)slice * 2 * E + e]);
}

// ---------------- final sum over 4 slices ----------------
__global__ void k_dsum(const float* __restrict__ psum, float* __restrict__ out, int n2e) {
    int e = blockIdx.x * blockDim.x + threadIdx.x;
    if (e < n2e) {
        float p0 = __builtin_nontemporal_load(&psum[e]);
        float p1 = __builtin_nontemporal_load(&psum[(size_t)n2e + e]);
        float p2 = __builtin_nontemporal_load(&psum[2 * (size_t)n2e + e]);
        float p3 = __builtin_nontemporal_load(&psum[3 * (size_t)n2e + e]);
        out[e] = (p0 + p1) + (p2 + p3);
    }
}

extern "C" void kernel_launch(void* const* d_in, const int* in_sizes, int n_in,
                              void* d_out, int out_size, void* d_ws, size_t ws_size,
                              hipStream_t stream) {
    const float* x   = (const float*)d_in[0];
    const int*   tei = (const int*)d_in[1];
    const int*   pos = (const int*)d_in[2];
    const int*   neg = (const int*)d_in[3];
    const float* W1  = (const float*)d_in[4];
    const float* b1  = (const float*)d_in[5];
    const float* W2  = (const float*)d_in[6];
    const float* b2  = (const float*)d_in[7];
    float* out = (float*)d_out;

    const int N = in_sizes[0] / NFEAT;    // 50000
    const int E = in_sizes[1] / 2;        // 800000
    const int NB = (N + 1023) / 1024;     // scan blocks (49)

    char* ws = (char*)d_ws;
    size_t off = 0;
    __half* g1s = (__half*)(ws + off);                 // [8][N][32] f16 (25.6MB)
    __half* g2s = (__half*)(ws + off);                 // [4][N][32] f16 (g1 dead)
    __half* zs  = (__half*)(ws + off + (size_t)N * OUTF * 2);   // [4][N][32] f16
    off += (size_t)N * HID * 2;
    __half* h1h  = (__half*)(ws + off);                // [N][256] f16 (25.6MB)
    float*  psum = (float*)(ws + off);                 // [4][2E] f32 (h1 dead after gemm2)
    off += (size_t)N * HID * 2;
    float*  dinv = (float*)(ws + off);  off += (size_t)N * 4;
    int* rowptr = (int*)(ws + off);     off += (size_t)(N + 1) * 4;
    int* cursor = (int*)(ws + off);     off += (size_t)N * 4;
    int* eidx   = (int*)(ws + off);     off += (size_t)E * 4;
    __half* W1t = (__half*)(ws + off);  off += (size_t)NFEAT * HID * 2;
    __half* W2t = (__half*)(ws + off);  off += (size_t)HID * OUTF * 2;
    int* excl   = (int*)(ws + off);     off += (size_t)N * 4;
    int* bsum   = (int*)(ws + off);     off += (size_t)(NB + 1) * 4;

    // 0) weight transpose+convert
    { dim3 g(NFEAT / 32, HID / 32);  k_wt<<<g, 256, 0, stream>>>(W1, W1t, NFEAT, HID); }
    { dim3 g(HID / 32, OUTF / 32);   k_wt<<<g, 256, 0, stream>>>(W2, W2t, HID, OUTF); }

    // 1) degree -> parallel scan -> CSR fill (shared by both layers)
    k_init_deg<<<(N + 255) / 256, 256, 0, stream>>>(dinv, N);
    k_count_deg<<<(E + 255) / 256, 256, 0, stream>>>(tei, dinv, E);
    k_scan1<<<NB, 1024, 0, stream>>>(dinv, excl, bsum, N);
    k_scan2<<<1, 64, 0, stream>>>(bsum, NB);
    k_scan3<<<(N + 256) / 256, 256, 0, stream>>>(dinv, excl, bsum, rowptr, cursor, N, NB);
    k_fill<<<(E + 255) / 256, 256, 0, stream>>>(tei, cursor, eidx, E);

    // 2) layer 1: g1s = (f16, [8][N][32]) dinv*(x@W1); h1 = row-major relu(...)
    {
        dim3 grid((N + 127) / 128, HID / 128);
        k_gemm_mfma<4, true, 5><<<grid, 256, 0, stream>>>(x, W1t, dinv, g1s, N, NFEAT, HID);
        int nblk = 8 * ((N + 3) / 4);
        k_aggs<8, true, false><<<nblk, 256, 0, stream>>>(rowptr, eidx, g1s, dinv, b1, h1h, N);
    }

    // 3) layer 2: g2s = (f16, [4][N][32]) dinv*(h1@W2); zs = sliced dinv*(agg+self)+b2
    {
        dim3 grid((N + 63) / 64, OUTF / 128);
        k_gemm_mfma<2, false, 5><<<grid, 256, 0, stream>>>(h1h, W2t, dinv, g2s, N, HID, OUTF);
        int nblk = 4 * ((N + 3) / 4);
        k_aggs<4, false, true><<<nblk, 256, 0, stream>>>(rowptr, eidx, g2s, dinv, b2, zs, N);
    }

    // 4) decode: sliced partial dots + final sum
    {
        int nblk = 4 * ((2 * E + 127) / 128);   // 4 waves x 32 edges per block
        k_decode<<<nblk, 256, 0, stream>>>(pos, neg, zs, psum, E, N);
        k_dsum<<<(2 * E + 255) / 256, 256, 0, stream>>>(psum, out, 2 * E);
    }
}